// Round 1
// baseline (233.493 us; speedup 1.0000x reference)
//
#include <hip/hip_runtime.h>
#include <hip/hip_bf16.h>

#define NT 256

__device__ __forceinline__ float2 cmulf(float2 a, float2 b) {
    return make_float2(a.x * b.x - a.y * b.y, a.x * b.y + a.y * b.x);
}

// Radix-2 DIT: input in bit-reversed order, output natural. Twiddle table
// tw[k] = exp(-2*pi*i*k/4096), k < 2048. Works for any N <= 4096 (power of 2):
// stage twiddle e^{-2pi i j/(2s)} = tw[j << (11 - log2(s))].
__device__ void fft_dit(float2* buf, const float2* tw, int N, bool inverse) {
    for (int s = 1, ls = 0; s < N; s <<= 1, ++ls) {
        for (int k = threadIdx.x; k < (N >> 1); k += NT) {
            int j = k & (s - 1);
            int base = ((k ^ j) << 1) | j;
            float2 w = tw[j << (11 - ls)];
            if (inverse) w.y = -w.y;
            float2 a = buf[base];
            float2 b = cmulf(buf[base + s], w);
            buf[base]     = make_float2(a.x + b.x, a.y + b.y);
            buf[base + s] = make_float2(a.x - b.x, a.y - b.y);
        }
        __syncthreads();
    }
}

// Radix-2 DIF: input natural, output bit-reversed.
__device__ void fft_dif(float2* buf, const float2* tw, int N, int log2N, bool inverse) {
    int ls = log2N - 1;
    for (int s = N >> 1; s >= 1; s >>= 1, --ls) {
        for (int k = threadIdx.x; k < (N >> 1); k += NT) {
            int j = k & (s - 1);
            int base = ((k ^ j) << 1) | j;
            float2 w = tw[j << (11 - ls)];
            if (inverse) w.y = -w.y;
            float2 a = buf[base];
            float2 b = buf[base + s];
            buf[base] = make_float2(a.x + b.x, a.y + b.y);
            float2 dv = make_float2(a.x - b.x, a.y - b.y);
            buf[base + s] = cmulf(dv, w);
        }
        __syncthreads();
    }
}

// One workgroup per d-channel: Cauchy sums -> at_roots -> FFT2048 -> K (time)
// -> zero-pad -> FFT4096 -> Khat[d][0..4095]
__global__ __launch_bounds__(256) void s4_khat_kernel(
    const float* __restrict__ Bmat, const float* __restrict__ Ct,
    const float* __restrict__ log_step,
    const float2* __restrict__ p, const float2* __restrict__ q,
    const float2* __restrict__ lmbda, const float2* __restrict__ omega,
    float2* __restrict__ Khat)
{
    __shared__ float2 buf[4096];
    __shared__ float2 tw[2048];
    __shared__ float  w0s[64];
    __shared__ float2 w1s[64], w2s[64], w3s[64], lams[64];

    const int tid = threadIdx.x;
    const int d = blockIdx.x;

    for (int k = tid; k < 2048; k += NT) {
        float a = -(float)k * (1.0f / 2048.0f);   // angle/pi = -2k/4096
        tw[k] = make_float2(cospif(a), sinpif(a));
    }
    if (tid < 64) {
        float b  = Bmat[d * 64 + tid];
        float ct = Ct[d * 64 + tid];
        float2 pp = p[tid], qq = q[tid];
        w0s[tid] = ct * b;
        w1s[tid] = make_float2(ct * pp.x, ct * pp.y);
        w2s[tid] = make_float2(qq.x * b, -qq.y * b);
        // conj(q)*p
        w3s[tid] = make_float2(qq.x * pp.x + qq.y * pp.y, qq.x * pp.y - qq.y * pp.x);
        lams[tid] = lmbda[tid];
    }
    __syncthreads();

    const float two_over_dt = 2.0f * expf(-log_step[d]);

    float2 at_reg[8];
    for (int i = 0; i < 8; ++i) {
        int l = tid + NT * i;
        float2 om = omega[l];
        float dnx = 1.0f + om.x, dny = om.y;
        float id2 = 1.0f / (dnx * dnx + dny * dny);
        float ivx = dnx * id2, ivy = -dny * id2;          // 1/(1+om)
        float ccx = 2.0f * ivx, ccy = 2.0f * ivy;          // c = 2/(1+om)
        float nmx = 1.0f - om.x, nmy = -om.y;              // 1-om
        float gx = two_over_dt * (nmx * ivx - nmy * ivy);  // g
        float gy = two_over_dt * (nmx * ivy + nmy * ivx);

        float k00x = 0.f, k00y = 0.f, k01x = 0.f, k01y = 0.f;
        float k10x = 0.f, k10y = 0.f, k11x = 0.f, k11y = 0.f;
        #pragma unroll 8
        for (int n = 0; n < 64; ++n) {
            float2 lam = lams[n];
            float dx = gx - lam.x, dy = gy - lam.y;
            float ir = 1.0f / (dx * dx + dy * dy);
            float rx = dx * ir, ry = -dy * ir;             // 1/(g-lam)
            float w0 = w0s[n];
            k00x += w0 * rx; k00y += w0 * ry;
            float2 w1 = w1s[n];
            k01x += w1.x * rx - w1.y * ry; k01y += w1.x * ry + w1.y * rx;
            float2 w2 = w2s[n];
            k10x += w2.x * rx - w2.y * ry; k10y += w2.x * ry + w2.y * rx;
            float2 w3 = w3s[n];
            k11x += w3.x * rx - w3.y * ry; k11y += w3.x * ry + w3.y * rx;
        }
        // t = (k01*k10)/(1+k11)
        float ntx = k01x * k10x - k01y * k10y;
        float nty = k01x * k10y + k01y * k10x;
        float ox = 1.0f + k11x, oy = k11y;
        float oid = 1.0f / (ox * ox + oy * oy);
        float tx = (ntx * ox + nty * oy) * oid;
        float ty = (nty * ox - ntx * oy) * oid;
        float inx = k00x - tx, iny = k00y - ty;
        at_reg[i] = make_float2(ccx * inx - ccy * iny, ccx * iny + ccy * inx);
    }
    for (int i = 0; i < 8; ++i) buf[tid + NT * i] = at_reg[i];
    __syncthreads();

    // forward FFT 2048 (DIF: natural in -> bit-reversed out)
    fft_dif(buf, tw, 2048, 11, false);

    // K[j] = Re(fft(at))[j] / 2048 ; gather from bit-reversed positions
    float kv[8];
    for (int i = 0; i < 8; ++i) {
        int j = tid + NT * i;
        kv[i] = buf[__brev((unsigned)j) >> 21].x * (1.0f / 2048.0f);
    }
    __syncthreads();
    for (int j = tid; j < 4096; j += NT) buf[j] = make_float2(0.f, 0.f);
    __syncthreads();
    for (int i = 0; i < 8; ++i) {
        int j = tid + NT * i;
        buf[__brev((unsigned)j) >> 20] = make_float2(kv[i], 0.f);
    }
    __syncthreads();

    // forward FFT 4096 (DIT: bit-reversed in -> natural out)
    fft_dit(buf, tw, 4096, false);

    float2* outp = Khat + (size_t)d * 4096;
    for (int j = tid; j < 4096; j += NT) outp[j] = buf[j];
}

// Pack/transpose: z[bp][d][l] = (u[2bp,l,d], u[2bp+1,l,d])
__global__ __launch_bounds__(256) void transpose_pack_kernel(
    const float* __restrict__ u, float2* __restrict__ z)
{
    __shared__ float2 tile[64][65];
    int blk = blockIdx.x;
    int lt  = blk & 31;
    int dt8 = (blk >> 5) & 7;
    int bp  = blk >> 8;
    const size_t ub0 = (size_t)(2 * bp) * 2048 * 512;
    const size_t ub1 = (size_t)(2 * bp + 1) * 2048 * 512;
    for (int r = 0; r < 16; ++r) {
        int idx = threadIdx.x + 256 * r;
        int row = idx >> 6;       // l within tile
        int col = idx & 63;       // d within tile
        size_t off = (size_t)(lt * 64 + row) * 512 + (dt8 * 64 + col);
        tile[col][row] = make_float2(u[ub0 + off], u[ub1 + off]);
    }
    __syncthreads();
    for (int r = 0; r < 16; ++r) {
        int idx = threadIdx.x + 256 * r;
        int row = idx >> 6;       // d within tile
        int col = idx & 63;       // l within tile
        z[((size_t)(bp * 512 + dt8 * 64 + row)) * 2048 + lt * 64 + col] = tile[row][col];
    }
}

// One workgroup per (bp,d): FFT4096(z) * Khat[d] -> inv FFT -> first 2048, in place.
__global__ __launch_bounds__(256) void s4_conv_kernel(
    float2* __restrict__ z, const float2* __restrict__ Khat)
{
    __shared__ float2 buf[4096];
    __shared__ float2 tw[2048];
    const int tid = threadIdx.x;
    const int d  = blockIdx.x & 511;
    const int bp = blockIdx.x >> 9;

    for (int k = tid; k < 2048; k += NT) {
        float a = -(float)k * (1.0f / 2048.0f);
        tw[k] = make_float2(cospif(a), sinpif(a));
    }
    float2* zr = z + ((size_t)(bp * 512 + d)) * 2048;
    float2 v[8];
    for (int i = 0; i < 8; ++i) v[i] = zr[tid + NT * i];
    for (int j = tid; j < 4096; j += NT) buf[j] = make_float2(0.f, 0.f);
    __syncthreads();
    for (int i = 0; i < 8; ++i) {
        int j = tid + NT * i;
        buf[__brev((unsigned)j) >> 20] = v[i];
    }
    __syncthreads();

    fft_dit(buf, tw, 4096, false);                 // forward, natural out

    const float2* kh = Khat + (size_t)d * 4096;
    for (int j = tid; j < 4096; j += NT) buf[j] = cmulf(buf[j], kh[j]);
    __syncthreads();

    fft_dif(buf, tw, 4096, 12, true);              // inverse, bit-reversed out

    const float sc = 1.0f / 4096.0f;
    for (int i = 0; i < 8; ++i) {
        int j = tid + NT * i;
        float2 xv = buf[__brev((unsigned)j) >> 20];
        zr[j] = make_float2(xv.x * sc, xv.y * sc);
    }
}

// out[b,l,d] = yz[bp][d][l].{x|y} + D[d]*u[b,l,d]
__global__ __launch_bounds__(256) void untranspose_kernel(
    const float2* __restrict__ yz, const float* __restrict__ u,
    const float* __restrict__ D, float* __restrict__ out)
{
    __shared__ float2 tile[64][65];
    int blk = blockIdx.x;
    int lt  = blk & 31;
    int dt8 = (blk >> 5) & 7;
    int bp  = blk >> 8;
    for (int r = 0; r < 16; ++r) {
        int idx = threadIdx.x + 256 * r;
        int row = idx >> 6;       // d within tile
        int col = idx & 63;       // l within tile
        float2 vv = yz[((size_t)(bp * 512 + dt8 * 64 + row)) * 2048 + lt * 64 + col];
        tile[col][row] = vv;      // store as [l][d]
    }
    __syncthreads();
    const size_t ub0 = (size_t)(2 * bp) * 2048 * 512;
    const size_t ub1 = (size_t)(2 * bp + 1) * 2048 * 512;
    for (int r = 0; r < 16; ++r) {
        int idx = threadIdx.x + 256 * r;
        int row = idx >> 6;       // l within tile
        int col = idx & 63;       // d within tile
        int dd = dt8 * 64 + col;
        float dv = D[dd];
        size_t off = (size_t)(lt * 64 + row) * 512 + dd;
        float2 vv = tile[row][col];
        out[ub0 + off] = vv.x + dv * u[ub0 + off];
        out[ub1 + off] = vv.y + dv * u[ub1 + off];
    }
}

extern "C" void kernel_launch(void* const* d_in, const int* in_sizes, int n_in,
                              void* d_out, int out_size, void* d_ws, size_t ws_size,
                              hipStream_t stream) {
    (void)in_sizes; (void)n_in; (void)out_size; (void)ws_size;
    const float*  u   = (const float*)d_in[0];
    const float*  Bm  = (const float*)d_in[1];
    const float*  Ct  = (const float*)d_in[2];
    const float*  D   = (const float*)d_in[3];
    const float*  ls  = (const float*)d_in[4];
    const float2* p   = (const float2*)d_in[5];
    const float2* q   = (const float2*)d_in[6];
    const float2* lm  = (const float2*)d_in[7];
    const float2* om  = (const float2*)d_in[8];
    float* out = (float*)d_out;

    float2* Khat = (float2*)d_ws;                                    // 16 MB
    float2* z    = (float2*)((char*)d_ws + (size_t)512 * 4096 * 8);  // 32 MB

    hipLaunchKernelGGL(s4_khat_kernel, dim3(512), dim3(256), 0, stream,
                       Bm, Ct, ls, p, q, lm, om, Khat);
    hipLaunchKernelGGL(transpose_pack_kernel, dim3(1024), dim3(256), 0, stream, u, z);
    hipLaunchKernelGGL(s4_conv_kernel, dim3(2048), dim3(256), 0, stream, z, Khat);
    hipLaunchKernelGGL(untranspose_kernel, dim3(1024), dim3(256), 0, stream, z, u, D, out);
}

// Round 2
// 165.095 us; speedup vs baseline: 1.4143x; 1.4143x over previous
//
#include <hip/hip_runtime.h>
#include <hip/hip_bf16.h>

#define NT 256

__device__ __forceinline__ float2 cmulf(float2 a, float2 b) {
    return make_float2(a.x * b.x - a.y * b.y, a.x * b.y + a.y * b.x);
}
__device__ __forceinline__ float2 cmulcf(float2 a, float2 b) { // a * conj(b)
    return make_float2(a.x * b.x + a.y * b.y, a.y * b.x - a.x * b.y);
}
__device__ __forceinline__ float2 cadd(float2 a, float2 b) { return make_float2(a.x + b.x, a.y + b.y); }
__device__ __forceinline__ float2 csub(float2 a, float2 b) { return make_float2(a.x - b.x, a.y - b.y); }
__device__ __forceinline__ int padi(int j) { return j + (j >> 3); }  // LDS anti-bank-conflict pad

// ---------------- Cauchy kernel: at[d][l], one thread per (d,l) ----------------
__global__ __launch_bounds__(256) void cauchy_kernel(
    const float* __restrict__ Bmat, const float* __restrict__ Ct,
    const float* __restrict__ log_step,
    const float2* __restrict__ p, const float2* __restrict__ q,
    const float2* __restrict__ lmbda, const float2* __restrict__ omega,
    float2* __restrict__ at)
{
    __shared__ float  w0s[64];
    __shared__ float2 w1s[64], w2s[64], w3s[64], lams[64];
    const int tid = threadIdx.x;
    const int d = blockIdx.x >> 3;
    const int l = ((blockIdx.x & 7) << 8) | tid;

    if (tid < 64) {
        float b  = Bmat[d * 64 + tid];
        float ct = Ct[d * 64 + tid];
        float2 pp = p[tid], qq = q[tid];
        w0s[tid] = ct * b;
        w1s[tid] = make_float2(ct * pp.x, ct * pp.y);
        w2s[tid] = make_float2(qq.x * b, -qq.y * b);
        w3s[tid] = make_float2(qq.x * pp.x + qq.y * pp.y, qq.x * pp.y - qq.y * pp.x); // conj(q)*p
        lams[tid] = lmbda[tid];
    }
    __syncthreads();

    const float two_over_dt = 2.0f * __expf(-log_step[d]);

    float2 om = omega[l];
    float dnx = 1.0f + om.x, dny = om.y;
    float id2 = __builtin_amdgcn_rcpf(dnx * dnx + dny * dny);
    float ivx = dnx * id2, ivy = -dny * id2;           // 1/(1+om)
    float ccx = 2.0f * ivx, ccy = 2.0f * ivy;           // c = 2/(1+om)
    float nmx = 1.0f - om.x, nmy = -om.y;               // 1-om
    float gx = two_over_dt * (nmx * ivx - nmy * ivy);   // g
    float gy = two_over_dt * (nmx * ivy + nmy * ivx);

    float k00x = 0.f, k00y = 0.f, k01x = 0.f, k01y = 0.f;
    float k10x = 0.f, k10y = 0.f, k11x = 0.f, k11y = 0.f;
    #pragma unroll 8
    for (int n = 0; n < 64; ++n) {
        float2 lam = lams[n];
        float dx = gx - lam.x, dy = gy - lam.y;
        float ir = __builtin_amdgcn_rcpf(dx * dx + dy * dy);
        float rx = dx * ir, ry = -dy * ir;              // 1/(g-lam)
        float w0 = w0s[n];
        k00x += w0 * rx; k00y += w0 * ry;
        float2 w1 = w1s[n];
        k01x += w1.x * rx - w1.y * ry; k01y += w1.x * ry + w1.y * rx;
        float2 w2 = w2s[n];
        k10x += w2.x * rx - w2.y * ry; k10y += w2.x * ry + w2.y * rx;
        float2 w3 = w3s[n];
        k11x += w3.x * rx - w3.y * ry; k11y += w3.x * ry + w3.y * rx;
    }
    float ntx = k01x * k10x - k01y * k10y;
    float nty = k01x * k10y + k01y * k10x;
    float ox = 1.0f + k11x, oy = k11y;
    float oid = __builtin_amdgcn_rcpf(ox * ox + oy * oy);
    float tx = (ntx * ox + nty * oy) * oid;
    float ty = (nty * ox - ntx * oy) * oid;
    float inx = k00x - tx, iny = k00y - ty;
    at[((size_t)d << 11) | l] = make_float2(ccx * inx - ccy * iny, ccx * iny + ccy * inx);
}

// ---------------- Khat kernel: at -> K (time) -> Khat (scrambled DIF order) ----------------
__global__ __launch_bounds__(256) void khat_kernel(
    const float2* __restrict__ at, float2* __restrict__ Khat)
{
    __shared__ float2 buf[4608];
    __shared__ float2 tw2k[1024];   // e^{-2pi i m/2048}
    __shared__ float2 tw4k[1024];   // e^{-2pi i m/4096}
    const int tid = threadIdx.x;
    const int d = blockIdx.x;

    for (int m = tid; m < 1024; m += NT) {
        float a2 = -(float)m * (1.0f / 1024.0f);
        tw2k[m] = make_float2(cospif(a2), sinpif(a2));
        float a4 = -(float)m * (1.0f / 2048.0f);
        tw4k[m] = make_float2(cospif(a4), sinpif(a4));
    }

    // load at (natural) -> LDS at bit-reversed(11) positions
    const float2* ap = at + ((size_t)d << 11);
    for (int i = 0; i < 8; ++i) {
        int l = tid + NT * i;
        buf[padi((int)(__brev((unsigned)l) >> 21))] = ap[l];
    }
    __syncthreads();

    // DIT radix-2, N=2048: bit-reversed in -> natural out
    for (int s = 1, ls = 0; s < 2048; s <<= 1, ++ls) {
        for (int k = tid; k < 1024; k += NT) {
            int j = k & (s - 1);
            int base = ((k ^ j) << 1) | j;
            float2 w = tw2k[j << (10 - ls)];
            float2 a = buf[padi(base)];
            float2 b = cmulf(buf[padi(base + s)], w);
            buf[padi(base)]     = cadd(a, b);
            buf[padi(base + s)] = csub(a, b);
        }
        __syncthreads();
    }

    // K[j] = Re/2048 ; rewrite as (K,0) for j<2048, zero 2048..4095
    float kv[8];
    for (int i = 0; i < 8; ++i) kv[i] = buf[padi(tid + NT * i)].x * (1.0f / 2048.0f);
    for (int i = 0; i < 8; ++i) buf[padi(tid + NT * i)] = make_float2(kv[i], 0.f);
    for (int j = 2048 + tid; j < 4096; j += NT) buf[padi(j)] = make_float2(0.f, 0.f);
    __syncthreads();

    // DIF radix-4, N=4096: natural in -> digit-scrambled out
    for (int s = 1024, sh = 0; s >= 1; s >>= 2, sh += 2) {
        for (int k = tid; k < 1024; k += NT) {
            int j = k & (s - 1);
            int base = ((k - j) << 2) + j;
            float2 x0 = buf[padi(base)];
            float2 x1 = buf[padi(base + s)];
            float2 x2 = buf[padi(base + 2 * s)];
            float2 x3 = buf[padi(base + 3 * s)];
            float2 a = cadd(x0, x2), b = csub(x0, x2);
            float2 c = cadd(x1, x3), e = csub(x1, x3);
            float2 bmie = make_float2(b.x + e.y, b.y - e.x);
            float2 bpie = make_float2(b.x - e.y, b.y + e.x);
            float2 w1 = tw4k[j << sh];
            float2 w2 = cmulf(w1, w1);
            float2 w3 = cmulf(w2, w1);
            buf[padi(base)]         = cadd(a, c);
            buf[padi(base + s)]     = cmulf(bmie, w1);
            buf[padi(base + 2 * s)] = cmulf(csub(a, c), w2);
            buf[padi(base + 3 * s)] = cmulf(bpie, w3);
        }
        __syncthreads();
    }

    // store scrambled Khat, fold in 1/4096 for the inverse transform
    float2* op = Khat + ((size_t)d << 12);
    for (int t = tid; t < 4096; t += NT) {
        float2 v = buf[padi(t)];
        op[t] = make_float2(v.x * (1.0f / 4096.0f), v.y * (1.0f / 4096.0f));
    }
}

// ---------------- transpose/pack: z[bp][d][l] = (u[2bp,l,d], u[2bp+1,l,d]) ----------------
__global__ __launch_bounds__(256) void transpose_pack_kernel(
    const float* __restrict__ u, float2* __restrict__ z)
{
    __shared__ float2 tile[64][65];
    int blk = blockIdx.x;
    int lt  = blk & 31;
    int dt8 = (blk >> 5) & 7;
    int bp  = blk >> 8;
    const size_t ub0 = (size_t)(2 * bp) * 2048 * 512;
    const size_t ub1 = (size_t)(2 * bp + 1) * 2048 * 512;
    for (int r = 0; r < 16; ++r) {
        int idx = threadIdx.x + 256 * r;
        int row = idx >> 6;       // l within tile
        int col = idx & 63;       // d within tile
        size_t off = (size_t)(lt * 64 + row) * 512 + (dt8 * 64 + col);
        tile[col][row] = make_float2(u[ub0 + off], u[ub1 + off]);
    }
    __syncthreads();
    for (int r = 0; r < 16; ++r) {
        int idx = threadIdx.x + 256 * r;
        int row = idx >> 6;       // d within tile
        int col = idx & 63;       // l within tile
        z[((size_t)(bp * 512 + dt8 * 64 + row)) * 2048 + lt * 64 + col] = tile[row][col];
    }
}

// ---------------- conv kernel: DIF4096 -> pointwise (scrambled) -> iDIT4096 ----------------
__global__ __launch_bounds__(256) void conv_kernel(
    float2* __restrict__ z, const float2* __restrict__ Khat)
{
    __shared__ float2 buf[4608];
    __shared__ float2 tw4k[1024];
    const int tid = threadIdx.x;
    const int d  = blockIdx.x & 511;
    const int bp = blockIdx.x >> 9;

    for (int m = tid; m < 1024; m += NT) {
        float a4 = -(float)m * (1.0f / 2048.0f);
        tw4k[m] = make_float2(cospif(a4), sinpif(a4));
    }
    float2* zr = z + ((size_t)(bp * 512 + d)) * 2048;
    float2 v[8];
    for (int i = 0; i < 8; ++i) v[i] = zr[tid + NT * i];
    for (int i = 0; i < 8; ++i) buf[padi(tid + NT * i)] = v[i];
    for (int j = 2048 + tid; j < 4096; j += NT) buf[padi(j)] = make_float2(0.f, 0.f);
    __syncthreads();

    // forward DIF radix-4 (natural in, scrambled out)
    for (int s = 1024, sh = 0; s >= 1; s >>= 2, sh += 2) {
        for (int k = tid; k < 1024; k += NT) {
            int j = k & (s - 1);
            int base = ((k - j) << 2) + j;
            float2 x0 = buf[padi(base)];
            float2 x1 = buf[padi(base + s)];
            float2 x2 = buf[padi(base + 2 * s)];
            float2 x3 = buf[padi(base + 3 * s)];
            float2 a = cadd(x0, x2), b = csub(x0, x2);
            float2 c = cadd(x1, x3), e = csub(x1, x3);
            float2 bmie = make_float2(b.x + e.y, b.y - e.x);
            float2 bpie = make_float2(b.x - e.y, b.y + e.x);
            float2 w1 = tw4k[j << sh];
            float2 w2 = cmulf(w1, w1);
            float2 w3 = cmulf(w2, w1);
            buf[padi(base)]         = cadd(a, c);
            buf[padi(base + s)]     = cmulf(bmie, w1);
            buf[padi(base + 2 * s)] = cmulf(csub(a, c), w2);
            buf[padi(base + 3 * s)] = cmulf(bpie, w3);
        }
        __syncthreads();
    }

    // pointwise multiply in scrambled domain (Khat stored in the same order)
    const float2* kh = Khat + ((size_t)d << 12);
    for (int t = tid; t < 4096; t += NT) buf[padi(t)] = cmulf(buf[padi(t)], kh[t]);
    __syncthreads();

    // inverse DIT radix-4 (scrambled in, natural out), scale already in Khat
    for (int s = 1, sh = 10; s <= 1024; s <<= 2, sh -= 2) {
        for (int k = tid; k < 1024; k += NT) {
            int j = k & (s - 1);
            int base = ((k - j) << 2) + j;
            float2 w1 = tw4k[j << sh];
            float2 w2 = cmulf(w1, w1);
            float2 w3 = cmulf(w2, w1);
            float2 y0 = buf[padi(base)];
            float2 z1 = cmulcf(buf[padi(base + s)], w1);
            float2 z2 = cmulcf(buf[padi(base + 2 * s)], w2);
            float2 z3 = cmulcf(buf[padi(base + 3 * s)], w3);
            float2 X0 = cadd(y0, z2), C = csub(y0, z2);
            float2 Bv = cadd(z1, z3);
            float2 dz = csub(z1, z3);
            float2 E = make_float2(-dz.y, dz.x);        // i*(z1-z3)
            buf[padi(base)]         = cadd(X0, Bv);
            buf[padi(base + s)]     = cadd(C, E);
            buf[padi(base + 2 * s)] = csub(X0, Bv);
            buf[padi(base + 3 * s)] = csub(C, E);
        }
        __syncthreads();
    }

    for (int i = 0; i < 8; ++i) zr[tid + NT * i] = buf[padi(tid + NT * i)];
}

// ---------------- untranspose + D*u epilogue ----------------
__global__ __launch_bounds__(256) void untranspose_kernel(
    const float2* __restrict__ yz, const float* __restrict__ u,
    const float* __restrict__ D, float* __restrict__ out)
{
    __shared__ float2 tile[64][65];
    int blk = blockIdx.x;
    int lt  = blk & 31;
    int dt8 = (blk >> 5) & 7;
    int bp  = blk >> 8;
    for (int r = 0; r < 16; ++r) {
        int idx = threadIdx.x + 256 * r;
        int row = idx >> 6;       // d within tile
        int col = idx & 63;       // l within tile
        float2 vv = yz[((size_t)(bp * 512 + dt8 * 64 + row)) * 2048 + lt * 64 + col];
        tile[col][row] = vv;
    }
    __syncthreads();
    const size_t ub0 = (size_t)(2 * bp) * 2048 * 512;
    const size_t ub1 = (size_t)(2 * bp + 1) * 2048 * 512;
    for (int r = 0; r < 16; ++r) {
        int idx = threadIdx.x + 256 * r;
        int row = idx >> 6;       // l within tile
        int col = idx & 63;       // d within tile
        int dd = dt8 * 64 + col;
        float dv = D[dd];
        size_t off = (size_t)(lt * 64 + row) * 512 + dd;
        float2 vv = tile[row][col];
        out[ub0 + off] = vv.x + dv * u[ub0 + off];
        out[ub1 + off] = vv.y + dv * u[ub1 + off];
    }
}

extern "C" void kernel_launch(void* const* d_in, const int* in_sizes, int n_in,
                              void* d_out, int out_size, void* d_ws, size_t ws_size,
                              hipStream_t stream) {
    (void)in_sizes; (void)n_in; (void)out_size; (void)ws_size;
    const float*  u   = (const float*)d_in[0];
    const float*  Bm  = (const float*)d_in[1];
    const float*  Ct  = (const float*)d_in[2];
    const float*  D   = (const float*)d_in[3];
    const float*  ls  = (const float*)d_in[4];
    const float2* p   = (const float2*)d_in[5];
    const float2* q   = (const float2*)d_in[6];
    const float2* lm  = (const float2*)d_in[7];
    const float2* om  = (const float2*)d_in[8];
    float* out = (float*)d_out;

    float2* Khat = (float2*)d_ws;                                    // 16.78 MB
    float2* z    = (float2*)((char*)d_ws + (size_t)512 * 4096 * 8);  // 33.55 MB
    float2* at   = z;  // aliased: consumed by khat_kernel before transpose overwrites z

    hipLaunchKernelGGL(cauchy_kernel, dim3(4096), dim3(256), 0, stream,
                       Bm, Ct, ls, p, q, lm, om, at);
    hipLaunchKernelGGL(khat_kernel, dim3(512), dim3(256), 0, stream, at, Khat);
    hipLaunchKernelGGL(transpose_pack_kernel, dim3(1024), dim3(256), 0, stream, u, z);
    hipLaunchKernelGGL(conv_kernel, dim3(2048), dim3(256), 0, stream, z, Khat);
    hipLaunchKernelGGL(untranspose_kernel, dim3(1024), dim3(256), 0, stream, z, u, D, out);
}

// Round 3
// 127.354 us; speedup vs baseline: 1.8334x; 1.2963x over previous
//
#include <hip/hip_runtime.h>
#include <hip/hip_bf16.h>

#define NT 256
#define R2f 0.70710678118654752f
#define CS1 0.92387953251128674f   // cos(pi/8)
#define SN1 0.38268343236508978f   // sin(pi/8)
#define PI2 6.2831853071795865f

__device__ __forceinline__ float2 cmulf(float2 a, float2 b) {
    return make_float2(a.x * b.x - a.y * b.y, a.x * b.y + a.y * b.x);
}
__device__ __forceinline__ float2 cadd(float2 a, float2 b) { return make_float2(a.x + b.x, a.y + b.y); }
__device__ __forceinline__ float2 csub(float2 a, float2 b) { return make_float2(a.x - b.x, a.y - b.y); }

// multiply by (wx, wy) fwd / (wx, -wy) inv
template<bool INV>
__device__ __forceinline__ float2 tww(float2 v, float wx, float wy) {
    float sy = INV ? -wy : wy;
    return make_float2(v.x * wx - v.y * sy, v.x * sy + v.y * wx);
}
// *( -i ) fwd ; *( +i ) inv
template<bool INV>
__device__ __forceinline__ float2 mul_mi(float2 v) {
    return INV ? make_float2(-v.y, v.x) : make_float2(v.y, -v.x);
}

template<bool INV>
__device__ __forceinline__ void dft4(float2& a, float2& b, float2& c, float2& d) {
    float2 t0 = cadd(a, c), t1 = csub(a, c);
    float2 t2 = cadd(b, d), t3 = csub(b, d);
    float2 jt3 = mul_mi<INV>(t3);
    a = cadd(t0, t2);
    c = csub(t0, t2);
    b = cadd(t1, jt3);
    d = csub(t1, jt3);
}

// Fully-unrolled 16-point DFT (fwd: W16^-1, inv: W16^+1), natural-order in/out.
template<bool INV>
__device__ __forceinline__ void fft16(float2 v[16]) {
    dft4<INV>(v[0], v[4], v[8],  v[12]);
    dft4<INV>(v[1], v[5], v[9],  v[13]);
    dft4<INV>(v[2], v[6], v[10], v[14]);
    dft4<INV>(v[3], v[7], v[11], v[15]);
    v[5]  = tww<INV>(v[5],  CS1, -SN1);   // W^1
    v[9]  = tww<INV>(v[9],  R2f, -R2f);   // W^2
    v[13] = tww<INV>(v[13], SN1, -CS1);   // W^3
    v[6]  = tww<INV>(v[6],  R2f, -R2f);   // W^2
    v[10] = mul_mi<INV>(v[10]);           // W^4
    v[14] = tww<INV>(v[14], -R2f, -R2f);  // W^6
    v[7]  = tww<INV>(v[7],  SN1, -CS1);   // W^3
    v[11] = tww<INV>(v[11], -R2f, -R2f);  // W^6
    v[15] = tww<INV>(v[15], -CS1,  SN1);  // W^9
    dft4<INV>(v[0],  v[1],  v[2],  v[3]);
    dft4<INV>(v[4],  v[5],  v[6],  v[7]);
    dft4<INV>(v[8],  v[9],  v[10], v[11]);
    dft4<INV>(v[12], v[13], v[14], v[15]);
    // digit-reverse base-4: X[k1*4+k0] sits at pos k0*4+k1 -> swap to natural
    float2 t;
    t = v[1];  v[1]  = v[4];  v[4]  = t;
    t = v[2];  v[2]  = v[8];  v[8]  = t;
    t = v[3];  v[3]  = v[12]; v[12] = t;
    t = v[6];  v[6]  = v[9];  v[9]  = t;
    t = v[7];  v[7]  = v[13]; v[13] = t;
    t = v[11]; v[11] = v[14]; v[14] = t;
}

// v[a] *= e^{-i*ang*a} (fwd) / e^{+i*ang*a} (inv)
template<bool INV>
__device__ __forceinline__ void twchain(float2 v[16], float ang) {
    float s, c;
    __sincosf(INV ? ang : -ang, &s, &c);
    float2 w = make_float2(c, s);
    float2 t = w;
    v[1] = cmulf(v[1], t);
    #pragma unroll
    for (int a = 2; a < 16; ++a) { t = cmulf(t, w); v[a] = cmulf(v[a], t); }
}

// 4096-pt FFT, 256 threads, 16 regs/thread.
// FWD input : thread m (=tid) holds x[m + 256*n2] in v[n2]
// FWD output: thread (hi=tid>>4, lo=tid&15) holds X[256*c + 16*lo + hi] in v[c]
// INV is the exact mirror (input in output layout, output in input layout).
template<bool INV>
__device__ void fft4096(float2 v[16], float2* lds, int tid) {
    const int hi = tid >> 4, lo = tid & 15;
    if (!INV) {
        fft16<false>(v);                                   // over n2 -> a
        twchain<false>(v, PI2 * (float)tid * (1.0f / 4096.0f));
        __syncthreads();
        #pragma unroll
        for (int a = 0; a < 16; ++a) lds[tid + 256 * a] = v[a];
        __syncthreads();
        #pragma unroll
        for (int m1 = 0; m1 < 16; ++m1) v[m1] = lds[(m1 * 16 + lo) + 256 * hi];
        fft16<false>(v);                                   // over m1 -> b
        twchain<false>(v, PI2 * (float)lo * (1.0f / 256.0f));
        __syncthreads();
        #pragma unroll
        for (int b = 0; b < 16; ++b) { int e = lo + 16 * b + 256 * hi; lds[e ^ b] = v[b]; }
        __syncthreads();
        #pragma unroll
        for (int m0 = 0; m0 < 16; ++m0) { int e = m0 + 16 * lo + 256 * hi; v[m0] = lds[e ^ lo]; }
        fft16<false>(v);                                   // over m0 -> c
    } else {
        fft16<true>(v);                                    // over c -> m0
        __syncthreads();
        #pragma unroll
        for (int m0 = 0; m0 < 16; ++m0) { int e = m0 + 16 * lo + 256 * hi; lds[e ^ lo] = v[m0]; }
        __syncthreads();
        #pragma unroll
        for (int b = 0; b < 16; ++b) { int e = lo + 16 * b + 256 * hi; v[b] = lds[e ^ b]; }
        twchain<true>(v, PI2 * (float)lo * (1.0f / 256.0f));
        fft16<true>(v);                                    // over b -> m1
        __syncthreads();
        #pragma unroll
        for (int m1 = 0; m1 < 16; ++m1) lds[(m1 * 16 + lo) + 256 * hi] = v[m1];
        __syncthreads();
        #pragma unroll
        for (int a = 0; a < 16; ++a) v[a] = lds[tid + 256 * a];
        twchain<true>(v, PI2 * (float)tid * (1.0f / 4096.0f));
        fft16<true>(v);                                    // over a -> n2
    }
}

// ---------------- Cauchy kernel: at[d][l], one thread per (d,l) ----------------
__global__ __launch_bounds__(256) void cauchy_kernel(
    const float* __restrict__ Bmat, const float* __restrict__ Ct,
    const float* __restrict__ log_step,
    const float2* __restrict__ p, const float2* __restrict__ q,
    const float2* __restrict__ lmbda, const float2* __restrict__ omega,
    float2* __restrict__ at)
{
    __shared__ float  w0s[64];
    __shared__ float2 w1s[64], w2s[64], w3s[64], lams[64];
    const int tid = threadIdx.x;
    const int d = blockIdx.x >> 3;
    const int l = ((blockIdx.x & 7) << 8) | tid;

    if (tid < 64) {
        float b  = Bmat[d * 64 + tid];
        float ct = Ct[d * 64 + tid];
        float2 pp = p[tid], qq = q[tid];
        w0s[tid] = ct * b;
        w1s[tid] = make_float2(ct * pp.x, ct * pp.y);
        w2s[tid] = make_float2(qq.x * b, -qq.y * b);
        w3s[tid] = make_float2(qq.x * pp.x + qq.y * pp.y, qq.x * pp.y - qq.y * pp.x); // conj(q)*p
        lams[tid] = lmbda[tid];
    }
    __syncthreads();

    const float two_over_dt = 2.0f * __expf(-log_step[d]);

    float2 om = omega[l];
    float dnx = 1.0f + om.x, dny = om.y;
    float id2 = __builtin_amdgcn_rcpf(dnx * dnx + dny * dny);
    float ivx = dnx * id2, ivy = -dny * id2;           // 1/(1+om)
    float ccx = 2.0f * ivx, ccy = 2.0f * ivy;           // c = 2/(1+om)
    float nmx = 1.0f - om.x, nmy = -om.y;               // 1-om
    float gx = two_over_dt * (nmx * ivx - nmy * ivy);   // g
    float gy = two_over_dt * (nmx * ivy + nmy * ivx);

    float k00x = 0.f, k00y = 0.f, k01x = 0.f, k01y = 0.f;
    float k10x = 0.f, k10y = 0.f, k11x = 0.f, k11y = 0.f;
    #pragma unroll 8
    for (int n = 0; n < 64; ++n) {
        float2 lam = lams[n];
        float dx = gx - lam.x, dy = gy - lam.y;
        float ir = __builtin_amdgcn_rcpf(dx * dx + dy * dy);
        float rx = dx * ir, ry = -dy * ir;              // 1/(g-lam)
        float w0 = w0s[n];
        k00x += w0 * rx; k00y += w0 * ry;
        float2 w1 = w1s[n];
        k01x += w1.x * rx - w1.y * ry; k01y += w1.x * ry + w1.y * rx;
        float2 w2 = w2s[n];
        k10x += w2.x * rx - w2.y * ry; k10y += w2.x * ry + w2.y * rx;
        float2 w3 = w3s[n];
        k11x += w3.x * rx - w3.y * ry; k11y += w3.x * ry + w3.y * rx;
    }
    float ntx = k01x * k10x - k01y * k10y;
    float nty = k01x * k10y + k01y * k10x;
    float ox = 1.0f + k11x, oy = k11y;
    float oid = __builtin_amdgcn_rcpf(ox * ox + oy * oy);
    float tx = (ntx * ox + nty * oy) * oid;
    float ty = (nty * ox - ntx * oy) * oid;
    float inx = k00x - tx, iny = k00y - ty;
    at[((size_t)d << 11) | l] = make_float2(ccx * inx - ccy * iny, ccx * iny + ccy * inx);
}

// ---------------- khat: G4 = F4096([at,0]); K = Re(G4[2j])/2048; Khat = F4096([K,0]) ----------------
__global__ __launch_bounds__(256) void khat_kernel(
    const float2* __restrict__ at, float2* __restrict__ Khat)
{
    __shared__ float2 lds[4096];
    const int tid = threadIdx.x;
    const int d = blockIdx.x;
    const int hi = tid >> 4, lo = tid & 15;
    float2 v[16];

    const float2* ap = at + ((size_t)d << 11);
    #pragma unroll
    for (int n2 = 0; n2 < 8; ++n2) v[n2] = ap[tid + 256 * n2];
    #pragma unroll
    for (int n2 = 8; n2 < 16; ++n2) v[n2] = make_float2(0.f, 0.f);

    fft4096<false>(v, lds, tid);     // thread (hi,lo) holds G4[256c+16lo+hi] in v[c]

    float* ldsf = (float*)lds;
    __syncthreads();
    if (!(hi & 1)) {                  // even output index <=> hi even
        int a2 = hi >> 1;
        #pragma unroll
        for (int c = 0; c < 16; ++c) {
            int j = 128 * c + 8 * lo + a2;               // j = k/2 in [0,2048)
            ldsf[j ^ ((j >> 5) & 3)] = v[c].x * (1.0f / (2048.0f * 4096.0f));
        }
    }
    __syncthreads();
    #pragma unroll
    for (int n2 = 0; n2 < 8; ++n2) {
        int j = tid + 256 * n2;
        v[n2] = make_float2(ldsf[j ^ ((j >> 5) & 3)], 0.f);
    }
    #pragma unroll
    for (int n2 = 8; n2 < 16; ++n2) v[n2] = make_float2(0.f, 0.f);

    fft4096<false>(v, lds, tid);     // Khat (scaled), same output layout

    float2* op = Khat + ((size_t)d << 12);
    #pragma unroll
    for (int c = 0; c < 16; ++c) op[c * 256 + tid] = v[c];
}

// ---------------- transpose/pack: z[bp][d][l] = (u[2bp,l,d], u[2bp+1,l,d]) ----------------
__global__ __launch_bounds__(256) void transpose_pack_kernel(
    const float* __restrict__ u, float2* __restrict__ z)
{
    __shared__ float2 tile[64][65];
    int blk = blockIdx.x;
    int lt  = blk & 31;
    int dt8 = (blk >> 5) & 7;
    int bp  = blk >> 8;
    const size_t ub0 = (size_t)(2 * bp) * 2048 * 512;
    const size_t ub1 = (size_t)(2 * bp + 1) * 2048 * 512;
    for (int r = 0; r < 16; ++r) {
        int idx = threadIdx.x + 256 * r;
        int row = idx >> 6;       // l within tile
        int col = idx & 63;       // d within tile
        size_t off = (size_t)(lt * 64 + row) * 512 + (dt8 * 64 + col);
        tile[col][row] = make_float2(u[ub0 + off], u[ub1 + off]);
    }
    __syncthreads();
    for (int r = 0; r < 16; ++r) {
        int idx = threadIdx.x + 256 * r;
        int row = idx >> 6;       // d within tile
        int col = idx & 63;       // l within tile
        z[((size_t)(bp * 512 + dt8 * 64 + row)) * 2048 + lt * 64 + col] = tile[row][col];
    }
}

// ---------------- conv: F4096([z,0]) * Khat -> inverse -> first 2048, in place ----------------
__global__ __launch_bounds__(256) void conv_kernel(
    float2* __restrict__ z, const float2* __restrict__ Khat)
{
    __shared__ float2 lds[4096];
    const int tid = threadIdx.x;
    const int d  = blockIdx.x & 511;
    const int bp = blockIdx.x >> 9;
    float2 v[16];

    float2* zr = z + ((size_t)(bp * 512 + d)) * 2048;
    #pragma unroll
    for (int n2 = 0; n2 < 8; ++n2) v[n2] = zr[tid + 256 * n2];
    #pragma unroll
    for (int n2 = 8; n2 < 16; ++n2) v[n2] = make_float2(0.f, 0.f);

    fft4096<false>(v, lds, tid);

    const float2* kh = Khat + ((size_t)d << 12);
    #pragma unroll
    for (int c = 0; c < 16; ++c) v[c] = cmulf(v[c], kh[c * 256 + tid]);

    fft4096<true>(v, lds, tid);

    #pragma unroll
    for (int n2 = 0; n2 < 8; ++n2) zr[tid + 256 * n2] = v[n2];
}

// ---------------- untranspose + D*u epilogue ----------------
__global__ __launch_bounds__(256) void untranspose_kernel(
    const float2* __restrict__ yz, const float* __restrict__ u,
    const float* __restrict__ D, float* __restrict__ out)
{
    __shared__ float2 tile[64][65];
    int blk = blockIdx.x;
    int lt  = blk & 31;
    int dt8 = (blk >> 5) & 7;
    int bp  = blk >> 8;
    for (int r = 0; r < 16; ++r) {
        int idx = threadIdx.x + 256 * r;
        int row = idx >> 6;       // d within tile
        int col = idx & 63;       // l within tile
        float2 vv = yz[((size_t)(bp * 512 + dt8 * 64 + row)) * 2048 + lt * 64 + col];
        tile[col][row] = vv;
    }
    __syncthreads();
    const size_t ub0 = (size_t)(2 * bp) * 2048 * 512;
    const size_t ub1 = (size_t)(2 * bp + 1) * 2048 * 512;
    for (int r = 0; r < 16; ++r) {
        int idx = threadIdx.x + 256 * r;
        int row = idx >> 6;       // l within tile
        int col = idx & 63;       // d within tile
        int dd = dt8 * 64 + col;
        float dv = D[dd];
        size_t off = (size_t)(lt * 64 + row) * 512 + dd;
        float2 vv = tile[row][col];
        out[ub0 + off] = vv.x + dv * u[ub0 + off];
        out[ub1 + off] = vv.y + dv * u[ub1 + off];
    }
}

extern "C" void kernel_launch(void* const* d_in, const int* in_sizes, int n_in,
                              void* d_out, int out_size, void* d_ws, size_t ws_size,
                              hipStream_t stream) {
    (void)in_sizes; (void)n_in; (void)out_size; (void)ws_size;
    const float*  u   = (const float*)d_in[0];
    const float*  Bm  = (const float*)d_in[1];
    const float*  Ct  = (const float*)d_in[2];
    const float*  D   = (const float*)d_in[3];
    const float*  ls  = (const float*)d_in[4];
    const float2* p   = (const float2*)d_in[5];
    const float2* q   = (const float2*)d_in[6];
    const float2* lm  = (const float2*)d_in[7];
    const float2* om  = (const float2*)d_in[8];
    float* out = (float*)d_out;

    float2* Khat = (float2*)d_ws;                                    // 16.78 MB
    float2* z    = (float2*)((char*)d_ws + (size_t)512 * 4096 * 8);  // 33.55 MB
    float2* at   = z;  // aliased: consumed by khat_kernel before transpose overwrites z

    hipLaunchKernelGGL(cauchy_kernel, dim3(4096), dim3(256), 0, stream,
                       Bm, Ct, ls, p, q, lm, om, at);
    hipLaunchKernelGGL(khat_kernel, dim3(512), dim3(256), 0, stream, at, Khat);
    hipLaunchKernelGGL(transpose_pack_kernel, dim3(1024), dim3(256), 0, stream, u, z);
    hipLaunchKernelGGL(conv_kernel, dim3(2048), dim3(256), 0, stream, z, Khat);
    hipLaunchKernelGGL(untranspose_kernel, dim3(1024), dim3(256), 0, stream, z, u, D, out);
}